// Round 10
// baseline (7477.290 us; speedup 1.0000x reference)
//
#include <hip/hip_runtime.h>

// MultiLayerRNN: B=128, T=1024, D_IN=256, H=512, C=1000
// Round 10: DATA-AS-FLAG. h/U stored bitwise-NOT-encoded (written <=> nonzero,
// since tanh/finite values never hit the all-ones bit patterns). Consumers
// poll the data itself (retry loads until every ushort/dword nonzero), then
// XOR-decode. Deletes the progress-flag array and 2 of 3 IC round trips per
// step. Producers never wait on consumers (full-history buffers, no WAR).
//   8 chains x {L0A,L0B,UA,UB,CA,CB} = 48 WGs x 512 thr, weights VGPR-resident,
//   "off"-form 64-bit-vaddr sc1 asm (validated r4/r5/r9). Zero LDS in hot loop.

typedef __attribute__((ext_vector_type(8))) short bf16x8_t;
typedef __attribute__((ext_vector_type(4))) float f32x4;
typedef __attribute__((ext_vector_type(4))) unsigned u32x4;
typedef unsigned long long u64;

#define NCH 8u
#define SPIN_CAP (1u << 14)

__device__ __align__(16) unsigned short g_W[3][512 * 512];   // bf16 [n][k]: Wh0, Wx1, Wh1
__device__ float g_b1[512];
__device__ __align__(16) unsigned short g_pre0T[1024u * 512u * 128u]; // bf16 [t][c][128r]
__device__ __align__(16) unsigned short g_h0H[NCH][1025][8192];       // slot s = ~h0[s-1], [16r][512c]
__device__ __align__(16) unsigned short g_h1H[NCH][1025][8192];       // slot s = ~h1[s-1]
__device__ __align__(16) unsigned g_UH[NCH][1024][8192];              // [t][512c][16r] ~f32bits

__device__ __forceinline__ unsigned short f2bf(float f) {
  unsigned u = __float_as_uint(f);
  u += 0x7fffu + ((u >> 16) & 1u);   // RNE
  return (unsigned short)(u >> 16);
}
__device__ __forceinline__ float bf2f(unsigned short h) {
  return __uint_as_float(((unsigned)h) << 16);
}
__device__ __forceinline__ bf16x8_t cvt8f(const float* p) {
  bf16x8_t r;
#pragma unroll
  for (int i = 0; i < 8; ++i) r[i] = (short)f2bf(p[i]);
  return r;
}
__device__ __forceinline__ float tanh_fast(float x) {
  float e = __expf(2.f * x);
  return 1.f - 2.f / (e + 1.f);
}

#define MF(a, b, c) __builtin_amdgcn_mfma_f32_16x16x32_bf16(a, b, c, 0, 0, 0)
#define WAITV0 do { asm volatile("s_waitcnt vmcnt(0)" ::: "memory"); __builtin_amdgcn_sched_barrier(0); } while (0)

// validated r4/r5/r9 patterns: "off"-form 64-bit per-lane vaddr, sc1 = IC-coherent
#define LDG16(dst, base, OFF) \
  asm volatile("global_load_dwordx4 %0, %1, off offset:" #OFF " sc1" : "=v"(dst) : "v"(base))
#define ST2(base, OFF, val) \
  asm volatile("global_store_short %0, %1, off offset:" #OFF " sc1" :: "v"(base), "v"(val))
#define STU4(base, OFF, val) \
  asm volatile("global_store_dwordx4 %0, %1, off offset:" #OFF " sc1" :: "v"(base), "v"(val))

// validity: every 16-bit lane nonzero (bf16 frags; 2B stores => per-ushort check)
__device__ __forceinline__ bool vfrag(bf16x8_t v) {
  union { bf16x8_t b; unsigned u[4]; } t; t.b = v;
  bool ok = true;
#pragma unroll
  for (int i = 0; i < 4; ++i) ok = ok && ((t.u[i] & 0xFFFFu) != 0u) && ((t.u[i] >> 16) != 0u);
  return ok;
}
__device__ __forceinline__ bool vu4(u32x4 v) {
  return (v[0] != 0u) && (v[1] != 0u) && (v[2] != 0u) && (v[3] != 0u);
}
__device__ __forceinline__ bf16x8_t dec(bf16x8_t v) {
  union { bf16x8_t b; unsigned u[4]; } t; t.b = v;
#pragma unroll
  for (int i = 0; i < 4; ++i) t.u[i] = ~t.u[i];
  return t.b;
}
__device__ __forceinline__ f32x4 decf(u32x4 v) {
  f32x4 r;
#pragma unroll
  for (int i = 0; i < 4; ++i) r[i] = __uint_as_float(~v[i]);
  return r;
}

// ---------------------------------------------------------------- prep
__global__ void prep_kernel(const float* __restrict__ Wh0_w, const float* __restrict__ Wx1_w,
                            const float* __restrict__ Wh1_w, const float* __restrict__ Wx1_b,
                            const float* __restrict__ Wh1_b) {
  size_t tid = (size_t)blockIdx.x * blockDim.x + threadIdx.x;
  size_t stride = (size_t)gridDim.x * blockDim.x;
  for (size_t i = tid; i < 512u * 512u; i += stride) {
    g_W[0][i] = f2bf(Wh0_w[i]);
    g_W[1][i] = f2bf(Wx1_w[i]);
    g_W[2][i] = f2bf(Wh1_w[i]);
  }
  for (size_t i = tid; i < 512u; i += stride) g_b1[i] = Wx1_b[i] + Wh1_b[i];
  uint4 z = {0u, 0u, 0u, 0u};
  uint4 f = {~0u, ~0u, ~0u, ~0u};
  // slot 0 = encoded h=0 (NOT(0x0000) = 0xFFFF per ushort)
  for (size_t i = tid; i < NCH * 1024u; i += stride) {
    size_t ch = i >> 10, o = i & 1023u;
    ((uint4*)&g_h0H[ch][0][0])[o] = f;
    ((uint4*)&g_h1H[ch][0][0])[o] = f;
  }
  // slots 1..1024 = 0 (invalid marker)
  size_t n1 = (size_t)NCH * 1024u * 1024u;
  for (size_t i = tid; i < n1; i += stride) {
    size_t ch = i >> 20, o = i & ((1u << 20) - 1u);
    ((uint4*)&g_h0H[ch][1][0])[o] = z;
    ((uint4*)&g_h1H[ch][1][0])[o] = z;
  }
  uint4* pu = (uint4*)&g_UH[0][0][0];
  size_t nu = sizeof(g_UH) / 16u;
  for (size_t i = tid; i < nu; i += stride) pu[i] = z;
}

// ---------------------------------------------------------------- pre0: x @ Wx0^T + biases -> [t][c][128r]
__global__ __launch_bounds__(512) void pre0_kernel(const float* __restrict__ x,
                                                   const float* __restrict__ Wx0_w,
                                                   const float* __restrict__ Wx0_b,
                                                   const float* __restrict__ Wh0_b) {
  const unsigned t = blockIdx.x;
  const unsigned lane = threadIdx.x & 63u, w = threadIdx.x >> 6;
  const unsigned lrow = lane & 15u, lko = (lane >> 4) * 8u, crow = (lane >> 4) * 4u;
  const unsigned ncol0 = w * 64u;
  f32x4 z4 = {0.f, 0.f, 0.f, 0.f};
  f32x4 acc[8][4];
#pragma unroll
  for (int a = 0; a < 8; ++a)
#pragma unroll
    for (int b = 0; b < 4; ++b) acc[a][b] = z4;

  for (unsigned kk = 0; kk < 8u; ++kk) {
    unsigned k0 = kk * 32u + lko;
    bf16x8_t bfr[4];
#pragma unroll
    for (unsigned nj = 0; nj < 4u; ++nj) {
      unsigned n = ncol0 + nj * 16u + lrow;
      bfr[nj] = cvt8f(Wx0_w + n * 256u + k0);
    }
#pragma unroll
    for (unsigned mi = 0; mi < 8u; ++mi) {
      unsigned m = mi * 16u + lrow;
      bf16x8_t afr = cvt8f(x + ((size_t)m * 1024u + t) * 256u + k0);
#pragma unroll
      for (unsigned nj = 0; nj < 4u; ++nj)
        acc[mi][nj] = MF(afr, bfr[nj], acc[mi][nj]);
    }
  }
#pragma unroll
  for (unsigned mi = 0; mi < 8u; ++mi)
#pragma unroll
    for (unsigned nj = 0; nj < 4u; ++nj) {
      unsigned col = ncol0 + nj * 16u + lrow;
      u64 pv = 0ull;
#pragma unroll
      for (unsigned r = 0; r < 4u; ++r) {
        float v = acc[mi][nj][r] + Wx0_b[col] + Wh0_b[col];
        pv |= ((u64)f2bf(v)) << (16u * r);
      }
      *(u64*)(&g_pre0T[((size_t)t * 512u + col) * 128u + mi * 16u + crow]) = pv;
    }
}

// ---------------------------------------------------------------- per-role persistent loop
// STAGE: 0 = L0 (h0 self-loop + pre0), 1 = U (U = h0@Wx1^T + b1), 2 = C (h1 self-loop + U)
template<int STAGE>
__device__ __forceinline__ void run_role(unsigned ch, unsigned hh) {
  const unsigned tid = threadIdx.x;
  const unsigned lane = tid & 63u, w = tid >> 6;
  const unsigned lrow = lane & 15u, kq = (lane >> 4) * 8u, crow4 = (lane >> 4) * 4u;
  const unsigned n0 = hh * 256u + w * 32u + lrow;      // wave's output col (per lane)

  // ---- B weights -> VGPRs once; frag f<8 = own k-half, f>=8 = sibling k-half ----
  bf16x8_t wB0[16], wB1[16];
  {
    const unsigned short* wp = g_W[STAGE];
#pragma unroll
    for (int f = 0; f < 16; ++f) {
      unsigned kfl = (STAGE == 1) ? (unsigned)f
                                  : ((f < 8) ? hh * 8u + (unsigned)f : (1u - hh) * 8u + (unsigned)(f - 8));
      wB0[f] = *(const bf16x8_t*)(wp + ((size_t)n0 * 512u + kfl * 32u + kq));
      wB1[f] = *(const bf16x8_t*)(wp + ((size_t)(n0 + 16u) * 512u + kfl * 32u + kq));
    }
  }
  float bu0 = 0.f, bu1 = 0.f;
  if (STAGE == 1) { bu0 = g_b1[n0]; bu1 = g_b1[n0 + 16u]; }

  // ---- uniform bases ----
  const unsigned short* aB = (STAGE == 2) ? &g_h1H[ch][0][0] : &g_h0H[ch][0][0];
  unsigned short* oB = (STAGE == 0) ? &g_h0H[ch][0][0] : &g_h1H[ch][0][0];

  const f32x4 z4 = {0.f, 0.f, 0.f, 0.f};

  for (unsigned t = 0; t < 1024u; ++t) {
    bf16x8_t x0, x1, x2, x3, x4, x5, x6, x7, x8, x9, x10, x11, x12, x13, x14, x15;
    f32x4 acc0 = z4, acc1 = z4;
    u32x4 ur0 = {0u, 0u, 0u, 0u}, ur1 = {0u, 0u, 0u, 0u};
    u64 p0a = 0ull, p0b = 0ull;

    if (STAGE == 0) {
      // pre0: written before rnn launch (kernel boundary) -> plain cached loads
      const unsigned short* pp = g_pre0T + ((size_t)t * 512u + n0) * 128u + ch * 16u + crow4;
      p0a = *(const u64*)pp;
      p0b = *(const u64*)(pp + 2048u);                    // +16 cols
    }

    if (STAGE != 1) {
      // ---- self-loop: A = h[t-1] = slot t. Own half valid by last step's
      //      drain+syncthreads; sibling half + U polled ON THE DATA. ----
      const unsigned short* pA = aB + (size_t)t * 8192u + lrow * 512u + kq;
      const unsigned short* pOwn = pA + hh * 256u;
      const unsigned short* pSb = pA + (1u - hh) * 256u;
      const unsigned* pU = (STAGE == 2) ? &g_UH[ch][t][(size_t)n0 * 16u + crow4] : (const unsigned*)0;
      LDG16(x0, pOwn, 0);   LDG16(x1, pOwn, 64);  LDG16(x2, pOwn, 128); LDG16(x3, pOwn, 192);
      LDG16(x4, pOwn, 256); LDG16(x5, pOwn, 320); LDG16(x6, pOwn, 384); LDG16(x7, pOwn, 448);
      LDG16(x8, pSb, 0);    LDG16(x9, pSb, 64);  LDG16(x10, pSb, 128); LDG16(x11, pSb, 192);
      LDG16(x12, pSb, 256); LDG16(x13, pSb, 320); LDG16(x14, pSb, 384); LDG16(x15, pSb, 448);
      if (STAGE == 2) { LDG16(ur0, pU, 0); LDG16(ur1, pU, 1024); }
      WAITV0;
      bool ok = vfrag(x8) && vfrag(x9) && vfrag(x10) && vfrag(x11) &&
                vfrag(x12) && vfrag(x13) && vfrag(x14) && vfrag(x15);
      if (STAGE == 2) ok = ok && vu4(ur0) && vu4(ur1);
      unsigned sp = 0;
      while (__any(!ok) && ++sp < SPIN_CAP) {
        LDG16(x8, pSb, 0);    LDG16(x9, pSb, 64);  LDG16(x10, pSb, 128); LDG16(x11, pSb, 192);
        LDG16(x12, pSb, 256); LDG16(x13, pSb, 320); LDG16(x14, pSb, 384); LDG16(x15, pSb, 448);
        if (STAGE == 2) { LDG16(ur0, pU, 0); LDG16(ur1, pU, 1024); }
        WAITV0;
        ok = vfrag(x8) && vfrag(x9) && vfrag(x10) && vfrag(x11) &&
             vfrag(x12) && vfrag(x13) && vfrag(x14) && vfrag(x15);
        if (STAGE == 2) ok = ok && vu4(ur0) && vu4(ur1);
      }
    } else {
      // ---- U: A = h0[t] = slot t+1, all 16 frags polled (L0A: 0-7, L0B: 8-15) ----
      const unsigned short* pA = aB + (size_t)(t + 1u) * 8192u + lrow * 512u + kq;
      LDG16(x0, pA, 0);    LDG16(x1, pA, 64);  LDG16(x2, pA, 128);  LDG16(x3, pA, 192);
      LDG16(x4, pA, 256);  LDG16(x5, pA, 320); LDG16(x6, pA, 384);  LDG16(x7, pA, 448);
      LDG16(x8, pA, 512);  LDG16(x9, pA, 576); LDG16(x10, pA, 640); LDG16(x11, pA, 704);
      LDG16(x12, pA, 768); LDG16(x13, pA, 832); LDG16(x14, pA, 896); LDG16(x15, pA, 960);
      WAITV0;
      bool ok = vfrag(x0) && vfrag(x1) && vfrag(x2) && vfrag(x3) &&
                vfrag(x4) && vfrag(x5) && vfrag(x6) && vfrag(x7) &&
                vfrag(x8) && vfrag(x9) && vfrag(x10) && vfrag(x11) &&
                vfrag(x12) && vfrag(x13) && vfrag(x14) && vfrag(x15);
      unsigned sp = 0;
      while (__any(!ok) && ++sp < SPIN_CAP) {
        LDG16(x0, pA, 0);    LDG16(x1, pA, 64);  LDG16(x2, pA, 128);  LDG16(x3, pA, 192);
        LDG16(x4, pA, 256);  LDG16(x5, pA, 320); LDG16(x6, pA, 384);  LDG16(x7, pA, 448);
        LDG16(x8, pA, 512);  LDG16(x9, pA, 576); LDG16(x10, pA, 640); LDG16(x11, pA, 704);
        LDG16(x12, pA, 768); LDG16(x13, pA, 832); LDG16(x14, pA, 896); LDG16(x15, pA, 960);
        WAITV0;
        ok = vfrag(x0) && vfrag(x1) && vfrag(x2) && vfrag(x3) &&
             vfrag(x4) && vfrag(x5) && vfrag(x6) && vfrag(x7) &&
             vfrag(x8) && vfrag(x9) && vfrag(x10) && vfrag(x11) &&
             vfrag(x12) && vfrag(x13) && vfrag(x14) && vfrag(x15);
      }
    }

    // decode (NOT) then MFMA
    x0 = dec(x0); x1 = dec(x1); x2 = dec(x2); x3 = dec(x3);
    x4 = dec(x4); x5 = dec(x5); x6 = dec(x6); x7 = dec(x7);
    x8 = dec(x8); x9 = dec(x9); x10 = dec(x10); x11 = dec(x11);
    x12 = dec(x12); x13 = dec(x13); x14 = dec(x14); x15 = dec(x15);
#define MM(F) do { acc0 = MF(x##F, wB0[F], acc0); acc1 = MF(x##F, wB1[F], acc1); } while (0)
    MM(0); MM(1); MM(2); MM(3); MM(4); MM(5); MM(6); MM(7);
    MM(8); MM(9); MM(10); MM(11); MM(12); MM(13); MM(14); MM(15);
#undef MM

    if (STAGE == 1) {
      unsigned* uo = &g_UH[ch][t][(size_t)n0 * 16u + crow4];
      u32x4 o0, o1;
#pragma unroll
      for (int j = 0; j < 4; ++j) {
        o0[j] = ~__float_as_uint(acc0[j] + bu0);
        o1[j] = ~__float_as_uint(acc1[j] + bu1);
      }
      STU4(uo, 0, o0); STU4(uo, 1024, o1);                // virgin slot: no WAR
    } else {
      unsigned short* ho = oB + (size_t)(t + 1u) * 8192u + crow4 * 512u + n0;
      f32x4 u0 = decf(ur0), u1 = decf(ur1);
      float e0, e1, e2, e3, f0, f1, f2, f3;
      if (STAGE == 0) {
        e0 = bf2f((unsigned short)(p0a));        e1 = bf2f((unsigned short)(p0a >> 16));
        e2 = bf2f((unsigned short)(p0a >> 32));  e3 = bf2f((unsigned short)(p0a >> 48));
        f0 = bf2f((unsigned short)(p0b));        f1 = bf2f((unsigned short)(p0b >> 16));
        f2 = bf2f((unsigned short)(p0b >> 32));  f3 = bf2f((unsigned short)(p0b >> 48));
      } else {
        e0 = u0[0]; e1 = u0[1]; e2 = u0[2]; e3 = u0[3];
        f0 = u1[0]; f1 = u1[1]; f2 = u1[2]; f3 = u1[3];
      }
      unsigned o;
      o = f2bf(tanh_fast(acc0[0] + e0)) ^ 0xFFFFu; ST2(ho, 0, o);
      o = f2bf(tanh_fast(acc0[1] + e1)) ^ 0xFFFFu; ST2(ho, 1024, o);
      o = f2bf(tanh_fast(acc0[2] + e2)) ^ 0xFFFFu; ST2(ho, 2048, o);
      o = f2bf(tanh_fast(acc0[3] + e3)) ^ 0xFFFFu; ST2(ho, 3072, o);
      o = f2bf(tanh_fast(acc1[0] + f0)) ^ 0xFFFFu; ST2(ho, 32, o);
      o = f2bf(tanh_fast(acc1[1] + f1)) ^ 0xFFFFu; ST2(ho, 1056, o);
      o = f2bf(tanh_fast(acc1[2] + f2)) ^ 0xFFFFu; ST2(ho, 2080, o);
      o = f2bf(tanh_fast(acc1[3] + f3)) ^ 0xFFFFu; ST2(ho, 3104, o);
    }

    // ---- own-half license for NEXT step: per-wave drain -> WG barrier ----
    WAITV0;
    __syncthreads();
  }
}

// ---------------------------------------------------------------- persistent recurrence
__global__ __launch_bounds__(512, 1) void rnn_kernel() {
  const unsigned wg = blockIdx.x;
  const unsigned ch = wg / 6u;
  const unsigned r = wg % 6u;
  const unsigned stage = r >> 1, hh = r & 1u;
  if (stage == 0u) run_role<0>(ch, hh);
  else if (stage == 1u) run_role<1>(ch, hh);
  else run_role<2>(ch, hh);
}

// ---------------------------------------------------------------- fc: h1_final @ fc_w^T + fc_b
__global__ __launch_bounds__(256) void fc_kernel(const float* __restrict__ fc_w,
                                                 const float* __restrict__ fc_b,
                                                 float* __restrict__ out) {
  const unsigned wg = blockIdx.x;
  const unsigned lane = threadIdx.x & 63u, w = threadIdx.x >> 6;
  const unsigned lrow = lane & 15u, lko = (lane >> 4) * 8u, crow = (lane >> 4) * 4u;
  const unsigned n0 = wg * 64u + w * 16u;
  f32x4 z4 = {0.f, 0.f, 0.f, 0.f};
  f32x4 acc[8];
#pragma unroll
  for (int a = 0; a < 8; ++a) acc[a] = z4;
  const unsigned n = n0 + lrow;
  for (unsigned kk = 0; kk < 16u; ++kk) {
    unsigned k0 = kk * 32u + lko;
    bf16x8_t bfr = {0, 0, 0, 0, 0, 0, 0, 0};
    if (n < 1000u) bfr = cvt8f(fc_w + n * 512u + k0);
#pragma unroll
    for (unsigned mi = 0; mi < 8u; ++mi) {
      bf16x8_t afr = dec(*(const bf16x8_t*)(&g_h1H[mi][1024][lrow * 512u + k0]));  // ~h1[1023]
      acc[mi] = MF(afr, bfr, acc[mi]);
    }
  }
#pragma unroll
  for (unsigned mi = 0; mi < 8u; ++mi)
#pragma unroll
    for (unsigned rr = 0; rr < 4u; ++rr) {
      unsigned row = mi * 16u + crow + rr;
      unsigned col = n0 + lrow;
      if (col < 1000u) out[row * 1000u + col] = acc[mi][rr] + fc_b[col];
    }
}

// ---------------------------------------------------------------- launch
extern "C" void kernel_launch(void* const* d_in, const int* in_sizes, int n_in,
                              void* d_out, int out_size, void* d_ws, size_t ws_size,
                              hipStream_t stream) {
  (void)in_sizes; (void)n_in; (void)out_size; (void)d_ws; (void)ws_size;
  const float* x     = (const float*)d_in[0];
  const float* Wx0_w = (const float*)d_in[1];
  const float* Wx0_b = (const float*)d_in[2];
  const float* Wh0_w = (const float*)d_in[3];
  const float* Wh0_b = (const float*)d_in[4];
  const float* Wx1_w = (const float*)d_in[5];
  const float* Wx1_b = (const float*)d_in[6];
  const float* Wh1_w = (const float*)d_in[7];
  const float* Wh1_b = (const float*)d_in[8];
  const float* fc_w  = (const float*)d_in[9];
  const float* fc_b  = (const float*)d_in[10];

  prep_kernel<<<1024, 256, 0, stream>>>(Wh0_w, Wx1_w, Wh1_w, Wx1_b, Wh1_b);
  pre0_kernel<<<1024, 512, 0, stream>>>(x, Wx0_w, Wx0_b, Wh0_b);
  rnn_kernel<<<48, 512, 0, stream>>>();
  fc_kernel<<<16, 256, 0, stream>>>(fc_w, fc_b, (float*)d_out);
}

// Round 11
// 6899.080 us; speedup vs baseline: 1.0838x; 1.0838x over previous
//
#include <hip/hip_runtime.h>

// MultiLayerRNN: B=128, T=1024, D_IN=256, H=512, C=1000
// Round 11: own-half h through LDS (same-WG producer/consumer => no IC RT),
// sibling half + U via IC data-as-flag (r10), NO store drains anywhere
// (full-history => no WAR; consumers validate per-ushort; consumer-side
// vmcnt(0) drains own stores in parallel with sib flight).
//   8 chains x {L0A,L0B,UA,UB,CA,CB} = 48 WGs x 512 thr.
//   L0/C: frags 0-7 (own, LDS) MFMA'd while sib frags 8-15 fly on IC.

typedef __attribute__((ext_vector_type(8))) short bf16x8_t;
typedef __attribute__((ext_vector_type(4))) float f32x4;
typedef __attribute__((ext_vector_type(4))) unsigned u32x4;
typedef unsigned long long u64;

#define NCH 8u
#define SPIN_CAP (1u << 14)

__device__ __align__(16) unsigned short g_W[3][512 * 512];   // bf16 [n][k]: Wh0, Wx1, Wh1
__device__ float g_b1[512];
__device__ __align__(16) unsigned short g_pre0T[1024u * 512u * 128u]; // bf16 [t][c][128r]
__device__ __align__(16) unsigned short g_h0H[NCH][1025][8192];       // slot s = ~h0[s-1], [16r][512c]
__device__ __align__(16) unsigned short g_h1H[NCH][1025][8192];       // slot s = ~h1[s-1]
__device__ __align__(16) unsigned g_UH[NCH][1024][8192];              // [t][512c][16r] ~f32bits

__device__ __forceinline__ unsigned short f2bf(float f) {
  unsigned u = __float_as_uint(f);
  u += 0x7fffu + ((u >> 16) & 1u);   // RNE
  return (unsigned short)(u >> 16);
}
__device__ __forceinline__ float bf2f(unsigned short h) {
  return __uint_as_float(((unsigned)h) << 16);
}
__device__ __forceinline__ bf16x8_t cvt8f(const float* p) {
  bf16x8_t r;
#pragma unroll
  for (int i = 0; i < 8; ++i) r[i] = (short)f2bf(p[i]);
  return r;
}
__device__ __forceinline__ float tanh_fast(float x) {
  float e = __expf(2.f * x);
  return 1.f - 2.f / (e + 1.f);
}

#define MF(a, b, c) __builtin_amdgcn_mfma_f32_16x16x32_bf16(a, b, c, 0, 0, 0)
#define WAITV0 do { asm volatile("s_waitcnt vmcnt(0)" ::: "memory"); __builtin_amdgcn_sched_barrier(0); } while (0)

// "off"-form 64-bit per-lane vaddr, sc1 = IC-coherent (validated r4/r5/r9/r10)
#define LDG16(dst, base, OFF) \
  asm volatile("global_load_dwordx4 %0, %1, off offset:" #OFF " sc1" : "=v"(dst) : "v"(base))
#define ST2(base, OFF, val) \
  asm volatile("global_store_short %0, %1, off offset:" #OFF " sc1" :: "v"(base), "v"(val))
#define STU4(base, OFF, val) \
  asm volatile("global_store_dwordx4 %0, %1, off offset:" #OFF " sc1" :: "v"(base), "v"(val))

// validity: every 16-bit lane nonzero (NOT-encoded data; tanh/finite never all-ones)
__device__ __forceinline__ bool vfrag(bf16x8_t v) {
  union { bf16x8_t b; unsigned u[4]; } t; t.b = v;
  bool ok = true;
#pragma unroll
  for (int i = 0; i < 4; ++i) ok = ok && ((t.u[i] & 0xFFFFu) != 0u) && ((t.u[i] >> 16) != 0u);
  return ok;
}
__device__ __forceinline__ bool vu4(u32x4 v) {
  return (v[0] != 0u) && (v[1] != 0u) && (v[2] != 0u) && (v[3] != 0u);
}
__device__ __forceinline__ bf16x8_t dec(bf16x8_t v) {
  union { bf16x8_t b; unsigned u[4]; } t; t.b = v;
#pragma unroll
  for (int i = 0; i < 4; ++i) t.u[i] = ~t.u[i];
  return t.b;
}
__device__ __forceinline__ f32x4 decf(u32x4 v) {
  f32x4 r;
#pragma unroll
  for (int i = 0; i < 4; ++i) r[i] = __uint_as_float(~v[i]);
  return r;
}

// ---------------------------------------------------------------- prep
__global__ void prep_kernel(const float* __restrict__ Wh0_w, const float* __restrict__ Wx1_w,
                            const float* __restrict__ Wh1_w, const float* __restrict__ Wx1_b,
                            const float* __restrict__ Wh1_b) {
  size_t tid = (size_t)blockIdx.x * blockDim.x + threadIdx.x;
  size_t stride = (size_t)gridDim.x * blockDim.x;
  for (size_t i = tid; i < 512u * 512u; i += stride) {
    g_W[0][i] = f2bf(Wh0_w[i]);
    g_W[1][i] = f2bf(Wx1_w[i]);
    g_W[2][i] = f2bf(Wh1_w[i]);
  }
  for (size_t i = tid; i < 512u; i += stride) g_b1[i] = Wx1_b[i] + Wh1_b[i];
  uint4 z = {0u, 0u, 0u, 0u};
  uint4 f = {~0u, ~0u, ~0u, ~0u};
  // slot 0 = encoded h=0 (NOT(0) = 0xFFFF per ushort)
  for (size_t i = tid; i < NCH * 1024u; i += stride) {
    size_t ch = i >> 10, o = i & 1023u;
    ((uint4*)&g_h0H[ch][0][0])[o] = f;
    ((uint4*)&g_h1H[ch][0][0])[o] = f;
  }
  // slots 1..1024 = 0 (invalid marker)
  size_t n1 = (size_t)NCH * 1024u * 1024u;
  for (size_t i = tid; i < n1; i += stride) {
    size_t ch = i >> 20, o = i & ((1u << 20) - 1u);
    ((uint4*)&g_h0H[ch][1][0])[o] = z;
    ((uint4*)&g_h1H[ch][1][0])[o] = z;
  }
  uint4* pu = (uint4*)&g_UH[0][0][0];
  size_t nu = sizeof(g_UH) / 16u;
  for (size_t i = tid; i < nu; i += stride) pu[i] = z;
}

// ---------------------------------------------------------------- pre0: x @ Wx0^T + biases -> [t][c][128r]
__global__ __launch_bounds__(512) void pre0_kernel(const float* __restrict__ x,
                                                   const float* __restrict__ Wx0_w,
                                                   const float* __restrict__ Wx0_b,
                                                   const float* __restrict__ Wh0_b) {
  const unsigned t = blockIdx.x;
  const unsigned lane = threadIdx.x & 63u, w = threadIdx.x >> 6;
  const unsigned lrow = lane & 15u, lko = (lane >> 4) * 8u, crow = (lane >> 4) * 4u;
  const unsigned ncol0 = w * 64u;
  f32x4 z4 = {0.f, 0.f, 0.f, 0.f};
  f32x4 acc[8][4];
#pragma unroll
  for (int a = 0; a < 8; ++a)
#pragma unroll
    for (int b = 0; b < 4; ++b) acc[a][b] = z4;

  for (unsigned kk = 0; kk < 8u; ++kk) {
    unsigned k0 = kk * 32u + lko;
    bf16x8_t bfr[4];
#pragma unroll
    for (unsigned nj = 0; nj < 4u; ++nj) {
      unsigned n = ncol0 + nj * 16u + lrow;
      bfr[nj] = cvt8f(Wx0_w + n * 256u + k0);
    }
#pragma unroll
    for (unsigned mi = 0; mi < 8u; ++mi) {
      unsigned m = mi * 16u + lrow;
      bf16x8_t afr = cvt8f(x + ((size_t)m * 1024u + t) * 256u + k0);
#pragma unroll
      for (unsigned nj = 0; nj < 4u; ++nj)
        acc[mi][nj] = MF(afr, bfr[nj], acc[mi][nj]);
    }
  }
#pragma unroll
  for (unsigned mi = 0; mi < 8u; ++mi)
#pragma unroll
    for (unsigned nj = 0; nj < 4u; ++nj) {
      unsigned col = ncol0 + nj * 16u + lrow;
      u64 pv = 0ull;
#pragma unroll
      for (unsigned r = 0; r < 4u; ++r) {
        float v = acc[mi][nj][r] + Wx0_b[col] + Wh0_b[col];
        pv |= ((u64)f2bf(v)) << (16u * r);
      }
      *(u64*)(&g_pre0T[((size_t)t * 512u + col) * 128u + mi * 16u + crow]) = pv;
    }
}

// ---------------------------------------------------------------- per-role persistent loop
// STAGE: 0 = L0 (h0 self-loop + pre0), 1 = U (U = h0@Wx1^T + b1), 2 = C (h1 self-loop + U)
template<int STAGE>
__device__ __forceinline__ void run_role(unsigned ch, unsigned hh, unsigned char* smem) {
  const unsigned tid = threadIdx.x;
  const unsigned lane = tid & 63u, w = tid >> 6;
  const unsigned lrow = lane & 15u, kq = (lane >> 4) * 8u, crow4 = (lane >> 4) * 4u;
  const unsigned n0 = hh * 256u + w * 32u + lrow;      // wave's output col (per lane)
  const unsigned cl = w * 32u + lrow;                  // col local to own half

  // ---- B weights -> VGPRs once; frag f<8 = own k-half, f>=8 = sibling k-half ----
  bf16x8_t wB0[16], wB1[16];
  {
    const unsigned short* wp = g_W[STAGE];
#pragma unroll
    for (int f = 0; f < 16; ++f) {
      unsigned kfl = (STAGE == 1) ? (unsigned)f
                                  : ((f < 8) ? hh * 8u + (unsigned)f : (1u - hh) * 8u + (unsigned)(f - 8));
      wB0[f] = *(const bf16x8_t*)(wp + ((size_t)n0 * 512u + kfl * 32u + kq));
      wB1[f] = *(const bf16x8_t*)(wp + ((size_t)(n0 + 16u) * 512u + kfl * 32u + kq));
    }
  }
  float bu0 = 0.f, bu1 = 0.f;
  if (STAGE == 1) { bu0 = g_b1[n0]; bu1 = g_b1[n0 + 16u]; }

  // ---- uniform bases ----
  const unsigned short* aB = (STAGE == 2) ? &g_h1H[ch][0][0] : &g_h0H[ch][0][0];
  unsigned short* oB = (STAGE == 0) ? &g_h0H[ch][0][0] : &g_h1H[ch][0][0];

  // ---- LDS prefill: slot 1 (read at t=0) = decoded zeros ----
  if (STAGE != 1) {
    for (unsigned i = tid; i < 2048u; i += 512u) ((unsigned*)(smem + 8192u))[i] = 0u;
    __syncthreads();
  }

  const f32x4 z4 = {0.f, 0.f, 0.f, 0.f};

  for (unsigned t = 0; t < 1024u; ++t) {
    bf16x8_t x0, x1, x2, x3, x4, x5, x6, x7, x8, x9, x10, x11, x12, x13, x14, x15;
    f32x4 acc0 = z4, acc1 = z4;
    u32x4 ur0 = {0u, 0u, 0u, 0u}, ur1 = {0u, 0u, 0u, 0u};
    u64 p0a = 0ull, p0b = 0ull;

    if (STAGE == 0) {
      const unsigned short* pp = g_pre0T + ((size_t)t * 512u + n0) * 128u + ch * 16u + crow4;
      p0a = *(const u64*)pp;
      p0b = *(const u64*)(pp + 2048u);                    // +16 cols
    }

    if (STAGE != 1) {
      // ---- sib half + (U for C): issue IC loads FIRST so they fly under own MFMAs ----
      const unsigned short* pSb = aB + (size_t)t * 8192u + lrow * 512u + kq + (1u - hh) * 256u;
      const unsigned* pU = (STAGE == 2) ? &g_UH[ch][t][(size_t)n0 * 16u + crow4] : (const unsigned*)0;
      LDG16(x8, pSb, 0);    LDG16(x9, pSb, 64);  LDG16(x10, pSb, 128); LDG16(x11, pSb, 192);
      LDG16(x12, pSb, 256); LDG16(x13, pSb, 320); LDG16(x14, pSb, 384); LDG16(x15, pSb, 448);
      if (STAGE == 2) { LDG16(ur0, pU, 0); LDG16(ur1, pU, 1024); }

      // ---- own half from LDS (decoded; slot (t+1)&1), MFMA frags 0-7 ----
      const unsigned rdB = ((t + 1u) & 1u) * 8192u + lrow * 512u;
      const unsigned swz = (lrow & 7u) << 4;
#define LRD(F) x##F = *(const bf16x8_t*)(smem + rdB + ((((unsigned)(F) * 32u + kq) * 2u) ^ swz))
      LRD(0); LRD(1); LRD(2); LRD(3); LRD(4); LRD(5); LRD(6); LRD(7);
#undef LRD
#define MM(F) do { acc0 = MF(x##F, wB0[F], acc0); acc1 = MF(x##F, wB1[F], acc1); } while (0)
      MM(0); MM(1); MM(2); MM(3); MM(4); MM(5); MM(6); MM(7);

      // ---- sib landed? validate + bounded retry (drains own stores in parallel) ----
      WAITV0;
      bool ok = vfrag(x8) && vfrag(x9) && vfrag(x10) && vfrag(x11) &&
                vfrag(x12) && vfrag(x13) && vfrag(x14) && vfrag(x15);
      unsigned sp = 0;
      while (__any(!ok) && ++sp < SPIN_CAP) {
        LDG16(x8, pSb, 0);    LDG16(x9, pSb, 64);  LDG16(x10, pSb, 128); LDG16(x11, pSb, 192);
        LDG16(x12, pSb, 256); LDG16(x13, pSb, 320); LDG16(x14, pSb, 384); LDG16(x15, pSb, 448);
        WAITV0;
        ok = vfrag(x8) && vfrag(x9) && vfrag(x10) && vfrag(x11) &&
             vfrag(x12) && vfrag(x13) && vfrag(x14) && vfrag(x15);
      }
      x8 = dec(x8); x9 = dec(x9); x10 = dec(x10); x11 = dec(x11);
      x12 = dec(x12); x13 = dec(x13); x14 = dec(x14); x15 = dec(x15);
      MM(8); MM(9); MM(10); MM(11); MM(12); MM(13); MM(14); MM(15);
#undef MM

      if (STAGE == 2) {                                   // U validated AFTER MFMAs
        const unsigned* pU2 = &g_UH[ch][t][(size_t)n0 * 16u + crow4];
        bool okU = vu4(ur0) && vu4(ur1);
        unsigned spu = 0;
        while (__any(!okU) && ++spu < SPIN_CAP) {
          LDG16(ur0, pU2, 0); LDG16(ur1, pU2, 1024);
          WAITV0;
          okU = vu4(ur0) && vu4(ur1);
        }
      }
    } else {
      // ---- U: A = h0[t] = slot t+1, all 16 frags data-as-flag ----
      const unsigned short* pA = aB + (size_t)(t + 1u) * 8192u + lrow * 512u + kq;
      LDG16(x0, pA, 0);    LDG16(x1, pA, 64);  LDG16(x2, pA, 128);  LDG16(x3, pA, 192);
      LDG16(x4, pA, 256);  LDG16(x5, pA, 320); LDG16(x6, pA, 384);  LDG16(x7, pA, 448);
      LDG16(x8, pA, 512);  LDG16(x9, pA, 576); LDG16(x10, pA, 640); LDG16(x11, pA, 704);
      LDG16(x12, pA, 768); LDG16(x13, pA, 832); LDG16(x14, pA, 896); LDG16(x15, pA, 960);
      WAITV0;
      bool ok = vfrag(x0) && vfrag(x1) && vfrag(x2) && vfrag(x3) &&
                vfrag(x4) && vfrag(x5) && vfrag(x6) && vfrag(x7) &&
                vfrag(x8) && vfrag(x9) && vfrag(x10) && vfrag(x11) &&
                vfrag(x12) && vfrag(x13) && vfrag(x14) && vfrag(x15);
      unsigned sp = 0;
      while (__any(!ok) && ++sp < SPIN_CAP) {
        LDG16(x0, pA, 0);    LDG16(x1, pA, 64);  LDG16(x2, pA, 128);  LDG16(x3, pA, 192);
        LDG16(x4, pA, 256);  LDG16(x5, pA, 320); LDG16(x6, pA, 384);  LDG16(x7, pA, 448);
        LDG16(x8, pA, 512);  LDG16(x9, pA, 576); LDG16(x10, pA, 640); LDG16(x11, pA, 704);
        LDG16(x12, pA, 768); LDG16(x13, pA, 832); LDG16(x14, pA, 896); LDG16(x15, pA, 960);
        WAITV0;
        ok = vfrag(x0) && vfrag(x1) && vfrag(x2) && vfrag(x3) &&
             vfrag(x4) && vfrag(x5) && vfrag(x6) && vfrag(x7) &&
             vfrag(x8) && vfrag(x9) && vfrag(x10) && vfrag(x11) &&
             vfrag(x12) && vfrag(x13) && vfrag(x14) && vfrag(x15);
      }
      x0 = dec(x0); x1 = dec(x1); x2 = dec(x2); x3 = dec(x3);
      x4 = dec(x4); x5 = dec(x5); x6 = dec(x6); x7 = dec(x7);
      x8 = dec(x8); x9 = dec(x9); x10 = dec(x10); x11 = dec(x11);
      x12 = dec(x12); x13 = dec(x13); x14 = dec(x14); x15 = dec(x15);
#define MM(F) do { acc0 = MF(x##F, wB0[F], acc0); acc1 = MF(x##F, wB1[F], acc1); } while (0)
      MM(0); MM(1); MM(2); MM(3); MM(4); MM(5); MM(6); MM(7);
      MM(8); MM(9); MM(10); MM(11); MM(12); MM(13); MM(14); MM(15);
#undef MM
    }

    if (STAGE == 1) {
      unsigned* uo = &g_UH[ch][t][(size_t)n0 * 16u + crow4];
      u32x4 o0, o1;
#pragma unroll
      for (int j = 0; j < 4; ++j) {
        o0[j] = ~__float_as_uint(acc0[j] + bu0);
        o1[j] = ~__float_as_uint(acc1[j] + bu1);
      }
      STU4(uo, 0, o0); STU4(uo, 1024, o1);                // fire-and-forget
    } else {
      unsigned short* ho = oB + (size_t)(t + 1u) * 8192u + crow4 * 512u + n0;
      f32x4 u0 = decf(ur0), u1 = decf(ur1);
      float e0, e1, e2, e3, f0, f1, f2, f3;
      if (STAGE == 0) {
        e0 = bf2f((unsigned short)(p0a));        e1 = bf2f((unsigned short)(p0a >> 16));
        e2 = bf2f((unsigned short)(p0a >> 32));  e3 = bf2f((unsigned short)(p0a >> 48));
        f0 = bf2f((unsigned short)(p0b));        f1 = bf2f((unsigned short)(p0b >> 16));
        f2 = bf2f((unsigned short)(p0b >> 32));  f3 = bf2f((unsigned short)(p0b >> 48));
      } else {
        e0 = u0[0]; e1 = u0[1]; e2 = u0[2]; e3 = u0[3];
        f0 = u1[0]; f1 = u1[1]; f2 = u1[2]; f3 = u1[3];
      }
      const unsigned wrB = (t & 1u) * 8192u;
      unsigned hv;
#define EMIT(J, ACC, EV, COFF, ICOFF) do { \
        hv = f2bf(tanh_fast((ACC)[J] + (EV))); \
        unsigned r_ = crow4 + (J); \
        *(unsigned short*)(smem + wrB + r_ * 512u + ((((cl + (COFF)) * 2u)) ^ ((r_ & 7u) << 4))) = (unsigned short)hv; \
        { unsigned enc = hv ^ 0xFFFFu; ST2(ho, ICOFF, enc); } \
      } while (0)
      EMIT(0, acc0, e0, 0u, 0);    EMIT(1, acc0, e1, 0u, 1024);
      EMIT(2, acc0, e2, 0u, 2048); EMIT(3, acc0, e3, 0u, 3072);
      EMIT(0, acc1, f0, 16u, 32);   EMIT(1, acc1, f1, 16u, 1056);
      EMIT(2, acc1, f2, 16u, 2080); EMIT(3, acc1, f3, 16u, 3104);
#undef EMIT
      __syncthreads();                                    // LDS slot handoff (only barrier/step)
    }
  }
}

// ---------------------------------------------------------------- persistent recurrence
__global__ __launch_bounds__(512, 1) void rnn_kernel() {
  __shared__ __align__(16) unsigned char smem[16384];
  const unsigned wg = blockIdx.x;
  const unsigned ch = wg / 6u;
  const unsigned r = wg % 6u;
  const unsigned stage = r >> 1, hh = r & 1u;
  if (stage == 0u) run_role<0>(ch, hh, smem);
  else if (stage == 1u) run_role<1>(ch, hh, smem);
  else run_role<2>(ch, hh, smem);
}

// ---------------------------------------------------------------- fc: h1_final @ fc_w^T + fc_b
__global__ __launch_bounds__(256) void fc_kernel(const float* __restrict__ fc_w,
                                                 const float* __restrict__ fc_b,
                                                 float* __restrict__ out) {
  const unsigned wg = blockIdx.x;
  const unsigned lane = threadIdx.x & 63u, w = threadIdx.x >> 6;
  const unsigned lrow = lane & 15u, lko = (lane >> 4) * 8u, crow = (lane >> 4) * 4u;
  const unsigned n0 = wg * 64u + w * 16u;
  f32x4 z4 = {0.f, 0.f, 0.f, 0.f};
  f32x4 acc[8];
#pragma unroll
  for (int a = 0; a < 8; ++a) acc[a] = z4;
  const unsigned n = n0 + lrow;
  for (unsigned kk = 0; kk < 16u; ++kk) {
    unsigned k0 = kk * 32u + lko;
    bf16x8_t bfr = {0, 0, 0, 0, 0, 0, 0, 0};
    if (n < 1000u) bfr = cvt8f(fc_w + n * 512u + k0);
#pragma unroll
    for (unsigned mi = 0; mi < 8u; ++mi) {
      bf16x8_t afr = dec(*(const bf16x8_t*)(&g_h1H[mi][1024][lrow * 512u + k0]));  // ~h1[1023]
      acc[mi] = MF(afr, bfr, acc[mi]);
    }
  }
#pragma unroll
  for (unsigned mi = 0; mi < 8u; ++mi)
#pragma unroll
    for (unsigned rr = 0; rr < 4u; ++rr) {
      unsigned row = mi * 16u + crow + rr;
      unsigned col = n0 + lrow;
      if (col < 1000u) out[row * 1000u + col] = acc[mi][rr] + fc_b[col];
    }
}

// ---------------------------------------------------------------- launch
extern "C" void kernel_launch(void* const* d_in, const int* in_sizes, int n_in,
                              void* d_out, int out_size, void* d_ws, size_t ws_size,
                              hipStream_t stream) {
  (void)in_sizes; (void)n_in; (void)out_size; (void)d_ws; (void)ws_size;
  const float* x     = (const float*)d_in[0];
  const float* Wx0_w = (const float*)d_in[1];
  const float* Wx0_b = (const float*)d_in[2];
  const float* Wh0_w = (const float*)d_in[3];
  const float* Wh0_b = (const float*)d_in[4];
  const float* Wx1_w = (const float*)d_in[5];
  const float* Wx1_b = (const float*)d_in[6];
  const float* Wh1_w = (const float*)d_in[7];
  const float* Wh1_b = (const float*)d_in[8];
  const float* fc_w  = (const float*)d_in[9];
  const float* fc_b  = (const float*)d_in[10];

  prep_kernel<<<1024, 256, 0, stream>>>(Wh0_w, Wx1_w, Wh1_w, Wx1_b, Wh1_b);
  pre0_kernel<<<1024, 512, 0, stream>>>(x, Wx0_w, Wx0_b, Wh0_b);
  rnn_kernel<<<48, 512, 0, stream>>>();
  fc_kernel<<<16, 256, 0, stream>>>(fc_w, fc_b, (float*)d_out);
}